// Round 5
// baseline (243.369 us; speedup 1.0000x reference)
//
#include <hip/hip_runtime.h>
#include <math.h>

#define NB 16      // batch
#define NN 4096    // nodes
#define NE 65536   // edges
#define DD 256     // feature dim
#define NR 4       // relations (excl. self)
#define VG 30000
#define VS 20000
#define NTG 118    // ceil(VG/256)  logits tiles (256 v per block)
#define NTS 79     // ceil(VS/256)
#define FTG 30     // ceil(VG/1024) final tiles
#define FTS 20     // ceil(VS/1024)
#define MCAP 1024  // match-list capacity per graph (E[matches] = 16)

// ws layout (float offsets):
#define WS_MC   0       // mcount [NB] int                 (16)
#define WS_CNT  16      // cnt [NB][NR] int                (64)
#define WS_H0T  80      // h0accT [DD][NB] (pre-ReLU)      (4096)
#define WS_MAT  4176    // matches [NB][MCAP] int          (16384)
#define WS_PM   20560   // per-tile max partials [16*197]  (3152)
#define WS_PS   23712   // per-tile sumexp partials        (3152)
// total 26864 floats = 107 KB; memset zeroes first 4176 floats (mc+cnt+h0accT)

__global__ __launch_bounds__(256) void k_scan(
    const int* __restrict__ ei, const int* __restrict__ etp,
    int* __restrict__ mcount, int* __restrict__ cnt, int* __restrict__ matches) {
  const int b = blockIdx.x;
  const int* src = ei + (size_t)b * 2 * NE;
  const int* dst = src + NE;
  const int* etb = etp + (size_t)b * NE;
  const int per = NE / gridDim.y;   // 4096
  const int base = blockIdx.y * per;
  for (int e0 = base + threadIdx.x * 4; e0 < base + per; e0 += blockDim.x * 4) {
    const int4 s = *reinterpret_cast<const int4*>(&src[e0]);
#pragma unroll
    for (int u = 0; u < 4; ++u) {
      const int sv = (u == 0) ? s.x : (u == 1) ? s.y : (u == 2) ? s.z : s.w;
      if (sv == 0) {
        const int e = e0 + u;
        const int r = etb[e];
        const int j = dst[e];
        atomicAdd(&cnt[b * NR + r], 1);
        const int idx = atomicAdd(&mcount[b], 1);
        if (idx < MCAP) matches[b * MCAP + idx] = (r << 12) | j;
      }
    }
  }
}

// grid (NR+1, 8): block (r, jt) builds u_r for all graphs (cheap, redundant per jt)
// then computes u[:, r, :] @ W_all[r][:, jt*32 .. +32] and atomicAdds into
// h0accT[j][b] (transposed). W is read exactly once device-wide.
__global__ __launch_bounds__(256) void k_h0(
    const float* __restrict__ x, const float* __restrict__ W_all,
    const int* __restrict__ mcount, const int* __restrict__ cnt,
    const int* __restrict__ matches, float* __restrict__ h0accT) {
  const int r = blockIdx.x;   // 0 = self, 1..NR
  const int jt = blockIdx.y;  // 0..7
  const int tid = threadIdx.x;
  __shared__ float us[NB][DD];        // 16 KB
  __shared__ float red[8][NB][32];    // 16 KB
  if (r == 0) {
    for (int b = 0; b < NB; ++b) us[b][tid] = x[((size_t)b * NN) * DD + tid];
  } else {
    for (int b = 0; b < NB; ++b) {
      float s = 0.f;
      const int n = min(mcount[b], MCAP);
      for (int m = 0; m < n; ++m) {
        const int mv = matches[b * MCAP + m];
        if ((mv >> 12) == r - 1) s += x[((size_t)b * NN + (mv & 4095)) * DD + tid];
      }
      us[b][tid] = s * (1.0f / fmaxf((float)cnt[b * NR + (r - 1)], 1.0f));
    }
  }
  __syncthreads();
  const int jl = tid & 31;
  const int kg = tid >> 5;            // 0..7, 32 k each
  const int j = jt * 32 + jl;
  const float* W = W_all + (size_t)r * DD * DD + j;
  float acc[NB];
#pragma unroll
  for (int b = 0; b < NB; ++b) acc[b] = 0.f;
  const int kb = kg * 32;
  for (int k0 = 0; k0 < 32; k0 += 8) {
    float w[8];
#pragma unroll
    for (int q = 0; q < 8; ++q) w[q] = W[(size_t)(kb + k0 + q) * DD];
#pragma unroll
    for (int q = 0; q < 8; ++q) {
#pragma unroll
      for (int b = 0; b < NB; ++b)
        acc[b] = fmaf(us[b][kb + k0 + q], w[q], acc[b]);
    }
  }
#pragma unroll
  for (int b = 0; b < NB; ++b) red[kg][b][jl] = acc[b];
  __syncthreads();
  const int bh = tid >> 5;
#pragma unroll
  for (int half = 0; half < 2; ++half) {
    const int b = bh + half * 8;
    float s = 0.f;
#pragma unroll
    for (int g = 0; g < 8; ++g) s += red[g][b][jl];
    atomicAdd(&h0accT[j * NB + b], s);
  }
}

// grid NTG+NTS blocks, 256 thr. Block = 256 v (lane owns float4).
// Wave w owns graphs 4w..4w+3 over the FULL K=256 -> no cross-wave reduce.
// h0 (ReLU'd) staged per-wave in LDS, broadcast ds_read_b128 in the loop.
__global__ __launch_bounds__(256) void k_logits(
    const float* __restrict__ Wg, const float* __restrict__ bg,
    const float* __restrict__ Wss, const float* __restrict__ bs,
    const float* __restrict__ h0accT, float* __restrict__ out,
    float* __restrict__ pm, float* __restrict__ ps) {
  const int blk = blockIdx.x;
  int tile, V, ntiles;
  const float *W, *bias;
  float *o, *pmh, *psh;
  if (blk < NTG) {
    tile = blk; V = VG; W = Wg; bias = bg; o = out;
    pmh = pm; psh = ps; ntiles = NTG;
  } else {
    tile = blk - NTG; V = VS; W = Wss; bias = bs; o = out + (size_t)NB * VG;
    pmh = pm + NB * NTG; psh = ps + NB * NTG; ntiles = NTS;
  }
  const int tid = threadIdx.x;
  const int wid = __builtin_amdgcn_readfirstlane(tid >> 6);  // wave id, uniform
  const int vl = tid & 63;
  const int V4 = V >> 2;
  const int v4 = tile * 64 + vl;        // float4 column index
  const bool valid = (v4 < V4);         // V%4==0 and 256|tile size -> all-or-nothing
  const int v4c = valid ? v4 : V4 - 1;

  // stage relu(h0) for this wave's 4 graphs: lw[wid][k] = {h[k][4w..4w+3]}
  __shared__ float4 lw[4][DD];          // 16 KB
  const float4* h0T4 = reinterpret_cast<const float4*>(h0accT);  // [DD][4]
#pragma unroll
  for (int q = 0; q < 4; ++q) {
    const int k = vl + 64 * q;
    float4 h = h0T4[k * 4 + wid];
    h.x = fmaxf(h.x, 0.f); h.y = fmaxf(h.y, 0.f);
    h.z = fmaxf(h.z, 0.f); h.w = fmaxf(h.w, 0.f);
    lw[wid][k] = h;
  }

  const float4* W4 = reinterpret_cast<const float4*>(W);
  float4 a0 = {0,0,0,0}, a1 = {0,0,0,0}, a2 = {0,0,0,0}, a3 = {0,0,0,0};
#pragma unroll 2
  for (int k0 = 0; k0 < DD; k0 += 16) {
    float4 wv[16];
#pragma unroll
    for (int u = 0; u < 16; ++u) wv[u] = W4[(size_t)(k0 + u) * V4 + v4c];
#pragma unroll
    for (int u = 0; u < 16; ++u) {
      const float4 h = lw[wid][k0 + u];
      a0.x = fmaf(wv[u].x, h.x, a0.x); a0.y = fmaf(wv[u].y, h.x, a0.y);
      a0.z = fmaf(wv[u].z, h.x, a0.z); a0.w = fmaf(wv[u].w, h.x, a0.w);
      a1.x = fmaf(wv[u].x, h.y, a1.x); a1.y = fmaf(wv[u].y, h.y, a1.y);
      a1.z = fmaf(wv[u].z, h.y, a1.z); a1.w = fmaf(wv[u].w, h.y, a1.w);
      a2.x = fmaf(wv[u].x, h.z, a2.x); a2.y = fmaf(wv[u].y, h.z, a2.y);
      a2.z = fmaf(wv[u].z, h.z, a2.z); a2.w = fmaf(wv[u].w, h.z, a2.w);
      a3.x = fmaf(wv[u].x, h.w, a3.x); a3.y = fmaf(wv[u].y, h.w, a3.y);
      a3.z = fmaf(wv[u].z, h.w, a3.z); a3.w = fmaf(wv[u].w, h.w, a3.w);
    }
  }
  const float4 bb = reinterpret_cast<const float4*>(bias)[v4c];
  a0.x += bb.x; a0.y += bb.y; a0.z += bb.z; a0.w += bb.w;
  a1.x += bb.x; a1.y += bb.y; a1.z += bb.z; a1.w += bb.w;
  a2.x += bb.x; a2.y += bb.y; a2.z += bb.z; a2.w += bb.w;
  a3.x += bb.x; a3.y += bb.y; a3.z += bb.z; a3.w += bb.w;

  float4* o4 = reinterpret_cast<float4*>(o);
  float4 av[4] = {a0, a1, a2, a3};
#pragma unroll
  for (int i = 0; i < 4; ++i) {
    const int b = 4 * wid + i;
    if (valid) o4[(size_t)b * V4 + v4] = av[i];
    float m = valid ? fmaxf(fmaxf(av[i].x, av[i].y), fmaxf(av[i].z, av[i].w))
                    : -INFINITY;
#pragma unroll
    for (int off = 32; off > 0; off >>= 1) m = fmaxf(m, __shfl_xor(m, off));
    float sx = valid ? (__expf(av[i].x - m) + __expf(av[i].y - m) +
                        __expf(av[i].z - m) + __expf(av[i].w - m)) : 0.f;
#pragma unroll
    for (int off = 32; off > 0; off >>= 1) sx += __shfl_xor(sx, off);
    if (vl == 0) { pmh[b * ntiles + tile] = m; psh[b * ntiles + tile] = sx; }
  }
}

// grid (FTG+FTS, NB): block re-reduces its head/graph partials to L, then
// subtracts from its 1024-v slice. Fuses old k_reduce + k_final.
__global__ __launch_bounds__(256) void k_final(
    const float* __restrict__ pm, const float* __restrict__ ps,
    float* __restrict__ out) {
  const int b = blockIdx.y;
  int head, t;
  if ((int)blockIdx.x < FTG) { head = 0; t = blockIdx.x; }
  else { head = 1; t = blockIdx.x - FTG; }
  const int V = head ? VS : VG;
  const int ntiles = head ? NTS : NTG;
  const float* pmh = pm + (head ? NB * NTG : 0) + b * ntiles;
  const float* psh = ps + (head ? NB * NTG : 0) + b * ntiles;
  const int tid = threadIdx.x;
  const int vl = tid & 63;
  const int wid = tid >> 6;

  float m = -INFINITY, s = 0.f;
  if (tid < ntiles) { m = pmh[tid]; s = psh[tid]; }
#pragma unroll
  for (int off = 32; off > 0; off >>= 1) {
    float mo = __shfl_xor(m, off);
    float so = __shfl_xor(s, off);
    float Mn = fmaxf(m, mo);
    float sn = ((m > -INFINITY) ? s * __expf(m - Mn) : 0.f) +
               ((mo > -INFINITY) ? so * __expf(mo - Mn) : 0.f);
    m = Mn; s = sn;
  }
  __shared__ float lm[4], ls[4];
  __shared__ float Lsh;
  if (vl == 0) { lm[wid] = m; ls[wid] = s; }
  __syncthreads();
  if (tid == 0) {
    float M = -INFINITY, S = 0.f;
#pragma unroll
    for (int w = 0; w < 4; ++w) {
      float mi = lm[w], si = ls[w];
      float Mn = fmaxf(M, mi);
      S = ((M > -INFINITY) ? S * __expf(M - Mn) : 0.f) +
          ((mi > -INFINITY) ? si * __expf(mi - Mn) : 0.f);
      M = Mn;
    }
    Lsh = M + logf(S);
  }
  __syncthreads();
  const float L = Lsh;
  float* o = out + (head ? (size_t)NB * VG : 0) + (size_t)b * V;
  const int v4 = t * 256 + tid;          // float4 index within this graph's row
  if (v4 * 4 < V) {
    float4* o4 = reinterpret_cast<float4*>(o);
    float4 x = o4[v4];
    x.x -= L; x.y -= L; x.z -= L; x.w -= L;
    o4[v4] = x;
  }
}

extern "C" void kernel_launch(void* const* d_in, const int* in_sizes, int n_in,
                              void* d_out, int out_size, void* d_ws, size_t ws_size,
                              hipStream_t stream) {
  const float* x     = (const float*)d_in[0];
  const float* W_all = (const float*)d_in[1];
  const float* Wg    = (const float*)d_in[2];
  const float* bg    = (const float*)d_in[3];
  const float* Ws    = (const float*)d_in[4];
  const float* bs    = (const float*)d_in[5];
  const int*   ei    = (const int*)d_in[6];
  const int*   etp   = (const int*)d_in[7];
  float* out = (float*)d_out;
  float* ws  = (float*)d_ws;

  int*   mcount  = (int*)(ws + WS_MC);
  int*   cnt     = (int*)(ws + WS_CNT);
  float* h0accT  = ws + WS_H0T;
  int*   matches = (int*)(ws + WS_MAT);
  float* pm      = ws + WS_PM;
  float* ps      = ws + WS_PS;

  // zero mcount + cnt + h0accT (contiguous; ws re-poisoned before every launch)
  hipMemsetAsync(d_ws, 0, 4176 * sizeof(float), stream);

  dim3 gscan(NB, 16);
  k_scan<<<gscan, 256, 0, stream>>>(ei, etp, mcount, cnt, matches);
  dim3 gh0(NR + 1, 8);
  k_h0<<<gh0, 256, 0, stream>>>(x, W_all, mcount, cnt, matches, h0accT);
  k_logits<<<NTG + NTS, 256, 0, stream>>>(Wg, bg, Ws, bs, h0accT, out, pm, ps);
  dim3 gfin(FTG + FTS, NB);
  k_final<<<gfin, 256, 0, stream>>>(pm, ps, out);
}

// Round 6
// 196.943 us; speedup vs baseline: 1.2357x; 1.2357x over previous
//
#include <hip/hip_runtime.h>
#include <math.h>

#define NB 16      // batch
#define NN 4096    // nodes
#define NE 65536   // edges
#define DD 256     // feature dim
#define NR 4       // relations (excl. self)
#define VG 30000
#define VS 20000
#define NTG 118    // ceil(7500/64)  v4-tiles of 64 float4 (256 v)
#define NTS 79     // ceil(5000/64)
#define FTG 30     // ceil(VG/1024) final tiles
#define FTS 20     // ceil(VS/1024)
#define KS  4      // k-chunks (64 k each)
#define P4TOT 12500  // total float4 columns (7500 g + 5000 s)
#define MCAP 1024

// ws layout (float offsets):
#define WS_MC   0       // mcount [NB] int                 (16)
#define WS_CNT  16      // cnt [NB][NR] int                (64)
#define WS_H0T  80      // h0accT [DD][NB] (pre-ReLU)      (4096)
#define WS_MAT  4176    // matches [NB][MCAP] int          (16384)
#define WS_PM   20560   // per-tile max partials           (3152)
#define WS_PS   23712   // per-tile sumexp partials        (3152)
#define WS_PART 26864   // partial [KS][NB][P4TOT] float4  (3200000 floats)
// total 3,226,864 floats ~= 12.9 MB

__global__ __launch_bounds__(256) void k_scan(
    const int* __restrict__ ei, const int* __restrict__ etp,
    int* __restrict__ mcount, int* __restrict__ cnt, int* __restrict__ matches) {
  const int b = blockIdx.x;
  const int* src = ei + (size_t)b * 2 * NE;
  const int* dst = src + NE;
  const int* etb = etp + (size_t)b * NE;
  const int per = NE / gridDim.y;   // 4096
  const int base = blockIdx.y * per;
  for (int e0 = base + threadIdx.x * 4; e0 < base + per; e0 += blockDim.x * 4) {
    const int4 s = *reinterpret_cast<const int4*>(&src[e0]);
#pragma unroll
    for (int u = 0; u < 4; ++u) {
      const int sv = (u == 0) ? s.x : (u == 1) ? s.y : (u == 2) ? s.z : s.w;
      if (sv == 0) {
        const int e = e0 + u;
        const int r = etb[e];
        const int j = dst[e];
        atomicAdd(&cnt[b * NR + r], 1);
        const int idx = atomicAdd(&mcount[b], 1);
        if (idx < MCAP) matches[b * MCAP + idx] = (r << 12) | j;
      }
    }
  }
}

// grid (NR+1, 8): block (r, jt): u_r for all graphs, then u @ W_all[r][:, jt*32..+32]
// atomicAdd into h0accT[j][b] (transposed, pre-ReLU). W read once device-wide.
__global__ __launch_bounds__(256) void k_h0(
    const float* __restrict__ x, const float* __restrict__ W_all,
    const int* __restrict__ mcount, const int* __restrict__ cnt,
    const int* __restrict__ matches, float* __restrict__ h0accT) {
  const int r = blockIdx.x;
  const int jt = blockIdx.y;
  const int tid = threadIdx.x;
  __shared__ float us[NB][DD];
  __shared__ float red[8][NB][32];
  if (r == 0) {
    for (int b = 0; b < NB; ++b) us[b][tid] = x[((size_t)b * NN) * DD + tid];
  } else {
    for (int b = 0; b < NB; ++b) {
      float s = 0.f;
      const int n = min(mcount[b], MCAP);
      for (int m = 0; m < n; ++m) {
        const int mv = matches[b * MCAP + m];
        if ((mv >> 12) == r - 1) s += x[((size_t)b * NN + (mv & 4095)) * DD + tid];
      }
      us[b][tid] = s * (1.0f / fmaxf((float)cnt[b * NR + (r - 1)], 1.0f));
    }
  }
  __syncthreads();
  const int jl = tid & 31;
  const int kg = tid >> 5;
  const int j = jt * 32 + jl;
  const float* W = W_all + (size_t)r * DD * DD + j;
  float acc[NB];
#pragma unroll
  for (int b = 0; b < NB; ++b) acc[b] = 0.f;
  const int kb = kg * 32;
  for (int k0 = 0; k0 < 32; k0 += 8) {
    float w[8];
#pragma unroll
    for (int q = 0; q < 8; ++q) w[q] = W[(size_t)(kb + k0 + q) * DD];
#pragma unroll
    for (int q = 0; q < 8; ++q) {
#pragma unroll
      for (int b = 0; b < NB; ++b)
        acc[b] = fmaf(us[b][kb + k0 + q], w[q], acc[b]);
    }
  }
#pragma unroll
  for (int b = 0; b < NB; ++b) red[kg][b][jl] = acc[b];
  __syncthreads();
  const int bh = tid >> 5;
#pragma unroll
  for (int half = 0; half < 2; ++half) {
    const int b = bh + half * 8;
    float s = 0.f;
#pragma unroll
    for (int g = 0; g < 8; ++g) s += red[g][b][jl];
    atomicAdd(&h0accT[j * NB + b], s);
  }
}

// grid (NTG+NTS, KS), 256 thr, VGPR cap 128 (launch_bounds min 4 waves/EU).
// Wave w handles k = chunk*64 + w*16 .. +16; lane owns one float4 column.
// 8-deep explicit load batches pinned with sched_barrier to keep loads in flight.
__global__ __launch_bounds__(256, 4) void k_logits4(
    const float* __restrict__ Wg, const float* __restrict__ Wss,
    const float* __restrict__ h0accT, float* __restrict__ partial) {
  const int blk = blockIdx.x;
  const int chunk = blockIdx.y;
  int tile, V4, c4base;
  const float* W;
  if (blk < NTG) { tile = blk; V4 = VG / 4; W = Wg; c4base = 0; }
  else { tile = blk - NTG; V4 = VS / 4; W = Wss; c4base = VG / 4; }
  const int tid = threadIdx.x;
  const int w = tid >> 6;
  const int l = tid & 63;
  const int v4 = tile * 64 + l;
  const bool valid = (v4 < V4);
  const int v4c = valid ? v4 : V4 - 1;

  // stage relu(h) rows [chunk*64 .. +64) x 16 graphs: 4 KB
  __shared__ float hs[64][16];
  {
    float4 hv = reinterpret_cast<const float4*>(h0accT)[chunk * 256 + tid];
    hv.x = fmaxf(hv.x, 0.f); hv.y = fmaxf(hv.y, 0.f);
    hv.z = fmaxf(hv.z, 0.f); hv.w = fmaxf(hv.w, 0.f);
    reinterpret_cast<float4*>(&hs[0][0])[tid] = hv;
  }
  __syncthreads();

  const float4* W4 = reinterpret_cast<const float4*>(W) + v4c;
  const int kg0 = chunk * 64 + w * 16;   // global k base for this wave
  float4 acc[16];
#pragma unroll
  for (int b = 0; b < NB; ++b) acc[b] = make_float4(0.f, 0.f, 0.f, 0.f);

#pragma unroll
  for (int half = 0; half < 2; ++half) {
    float4 wv[8];
#pragma unroll
    for (int u = 0; u < 8; ++u)
      wv[u] = W4[(size_t)(kg0 + half * 8 + u) * V4];
    __builtin_amdgcn_sched_barrier(0);   // keep the 8 loads issued before FMAs
#pragma unroll
    for (int u = 0; u < 8; ++u) {
      const int kk = w * 16 + half * 8 + u;
#pragma unroll
      for (int bq = 0; bq < 4; ++bq) {
        const float4 h4 = *reinterpret_cast<const float4*>(&hs[kk][bq * 4]);
        float4* A = &acc[bq * 4];
        A[0].x = fmaf(wv[u].x, h4.x, A[0].x); A[0].y = fmaf(wv[u].y, h4.x, A[0].y);
        A[0].z = fmaf(wv[u].z, h4.x, A[0].z); A[0].w = fmaf(wv[u].w, h4.x, A[0].w);
        A[1].x = fmaf(wv[u].x, h4.y, A[1].x); A[1].y = fmaf(wv[u].y, h4.y, A[1].y);
        A[1].z = fmaf(wv[u].z, h4.y, A[1].z); A[1].w = fmaf(wv[u].w, h4.y, A[1].w);
        A[2].x = fmaf(wv[u].x, h4.z, A[2].x); A[2].y = fmaf(wv[u].y, h4.z, A[2].y);
        A[2].z = fmaf(wv[u].z, h4.z, A[2].z); A[2].w = fmaf(wv[u].w, h4.z, A[2].w);
        A[3].x = fmaf(wv[u].x, h4.w, A[3].x); A[3].y = fmaf(wv[u].y, h4.w, A[3].y);
        A[3].z = fmaf(wv[u].z, h4.w, A[3].z); A[3].w = fmaf(wv[u].w, h4.w, A[3].w);
      }
    }
  }

  // cross-wave reduce (4 waves hold disjoint k-subranges)
  __shared__ float4 red[3][NB][64];   // 48 KB
  if (w > 0) {
#pragma unroll
    for (int b = 0; b < NB; ++b) red[w - 1][b][l] = acc[b];
  }
  __syncthreads();
  if (w == 0) {
#pragma unroll
    for (int b = 0; b < NB; ++b) {
      float4 s = acc[b];
#pragma unroll
      for (int jj = 0; jj < 3; ++jj) {
        const float4 rr = red[jj][b][l];
        s.x += rr.x; s.y += rr.y; s.z += rr.z; s.w += rr.w;
      }
      acc[b] = s;
    }
    if (valid) {
      float4* p4 = reinterpret_cast<float4*>(partial);
      const int c4g = c4base + v4;
#pragma unroll
      for (int b = 0; b < NB; ++b)
        p4[(size_t)(chunk * NB + b) * P4TOT + c4g] = acc[b];
    }
  }
}

// grid NTG+NTS, 256 thr: combine KS chunk partials + bias -> out, softmax partials.
// Wave w owns graphs 4w..4w+3.
__global__ __launch_bounds__(256) void k_comb(
    const float* __restrict__ partial, const float* __restrict__ bg,
    const float* __restrict__ bs, float* __restrict__ out,
    float* __restrict__ pm, float* __restrict__ ps) {
  const int blk = blockIdx.x;
  int tile, V4, c4base, ntiles;
  const float* bias;
  float *o, *pmh, *psh;
  if (blk < NTG) {
    tile = blk; V4 = VG / 4; c4base = 0; bias = bg; o = out;
    pmh = pm; psh = ps; ntiles = NTG;
  } else {
    tile = blk - NTG; V4 = VS / 4; c4base = VG / 4; bias = bs;
    o = out + (size_t)NB * VG;
    pmh = pm + NB * NTG; psh = ps + NB * NTG; ntiles = NTS;
  }
  const int tid = threadIdx.x;
  const int w = tid >> 6;
  const int vl = tid & 63;
  const int v4 = tile * 64 + vl;
  const bool valid = (v4 < V4);
  const int v4c = valid ? v4 : V4 - 1;
  const int c4g = c4base + v4c;
  const float4 bb = reinterpret_cast<const float4*>(bias)[v4c];
  const float4* p4 = reinterpret_cast<const float4*>(partial);
  float4* o4 = reinterpret_cast<float4*>(o);
#pragma unroll
  for (int i = 0; i < 4; ++i) {
    const int b = 4 * w + i;
    float4 s = bb;
#pragma unroll
    for (int c = 0; c < KS; ++c) {
      const float4 pp = p4[(size_t)(c * NB + b) * P4TOT + c4g];
      s.x += pp.x; s.y += pp.y; s.z += pp.z; s.w += pp.w;
    }
    if (valid) o4[(size_t)b * V4 + v4] = s;
    float m = valid ? fmaxf(fmaxf(s.x, s.y), fmaxf(s.z, s.w)) : -INFINITY;
#pragma unroll
    for (int off = 32; off > 0; off >>= 1) m = fmaxf(m, __shfl_xor(m, off));
    float sx = valid ? (__expf(s.x - m) + __expf(s.y - m) +
                        __expf(s.z - m) + __expf(s.w - m)) : 0.f;
#pragma unroll
    for (int off = 32; off > 0; off >>= 1) sx += __shfl_xor(sx, off);
    if (vl == 0) { pmh[b * ntiles + tile] = m; psh[b * ntiles + tile] = sx; }
  }
}

// grid (FTG+FTS, NB): re-reduce partials to L, subtract from 1024-v slice.
__global__ __launch_bounds__(256) void k_fin(
    const float* __restrict__ pm, const float* __restrict__ ps,
    float* __restrict__ out) {
  const int b = blockIdx.y;
  int head, t;
  if ((int)blockIdx.x < FTG) { head = 0; t = blockIdx.x; }
  else { head = 1; t = blockIdx.x - FTG; }
  const int V = head ? VS : VG;
  const int ntiles = head ? NTS : NTG;
  const float* pmh = pm + (head ? NB * NTG : 0) + b * ntiles;
  const float* psh = ps + (head ? NB * NTG : 0) + b * ntiles;
  const int tid = threadIdx.x;
  const int vl = tid & 63;
  const int wid = tid >> 6;

  float m = -INFINITY, s = 0.f;
  if (tid < ntiles) { m = pmh[tid]; s = psh[tid]; }
#pragma unroll
  for (int off = 32; off > 0; off >>= 1) {
    float mo = __shfl_xor(m, off);
    float so = __shfl_xor(s, off);
    float Mn = fmaxf(m, mo);
    float sn = ((m > -INFINITY) ? s * __expf(m - Mn) : 0.f) +
               ((mo > -INFINITY) ? so * __expf(mo - Mn) : 0.f);
    m = Mn; s = sn;
  }
  __shared__ float lm[4], ls[4];
  __shared__ float Lsh;
  if (vl == 0) { lm[wid] = m; ls[wid] = s; }
  __syncthreads();
  if (tid == 0) {
    float M = -INFINITY, S = 0.f;
#pragma unroll
    for (int wv = 0; wv < 4; ++wv) {
      float mi = lm[wv], si = ls[wv];
      float Mn = fmaxf(M, mi);
      S = ((M > -INFINITY) ? S * __expf(M - Mn) : 0.f) +
          ((mi > -INFINITY) ? si * __expf(mi - Mn) : 0.f);
      M = Mn;
    }
    Lsh = M + logf(S);
  }
  __syncthreads();
  const float L = Lsh;
  float* o = out + (head ? (size_t)NB * VG : 0) + (size_t)b * V;
  const int v4 = t * 256 + tid;
  if (v4 * 4 < V) {
    float4* o4 = reinterpret_cast<float4*>(o);
    float4 x = o4[v4];
    x.x -= L; x.y -= L; x.z -= L; x.w -= L;
    o4[v4] = x;
  }
}

extern "C" void kernel_launch(void* const* d_in, const int* in_sizes, int n_in,
                              void* d_out, int out_size, void* d_ws, size_t ws_size,
                              hipStream_t stream) {
  const float* x     = (const float*)d_in[0];
  const float* W_all = (const float*)d_in[1];
  const float* Wg    = (const float*)d_in[2];
  const float* bg    = (const float*)d_in[3];
  const float* Ws    = (const float*)d_in[4];
  const float* bs    = (const float*)d_in[5];
  const int*   ei    = (const int*)d_in[6];
  const int*   etp   = (const int*)d_in[7];
  float* out = (float*)d_out;
  float* ws  = (float*)d_ws;

  int*   mcount  = (int*)(ws + WS_MC);
  int*   cnt     = (int*)(ws + WS_CNT);
  float* h0accT  = ws + WS_H0T;
  int*   matches = (int*)(ws + WS_MAT);
  float* pm      = ws + WS_PM;
  float* ps      = ws + WS_PS;
  float* part    = ws + WS_PART;

  // zero mcount + cnt + h0accT (contiguous prefix)
  hipMemsetAsync(d_ws, 0, 4176 * sizeof(float), stream);

  dim3 gscan(NB, 16);
  k_scan<<<gscan, 256, 0, stream>>>(ei, etp, mcount, cnt, matches);
  dim3 gh0(NR + 1, 8);
  k_h0<<<gh0, 256, 0, stream>>>(x, W_all, mcount, cnt, matches, h0accT);
  dim3 glog(NTG + NTS, KS);
  k_logits4<<<glog, 256, 0, stream>>>(Wg, Ws, h0accT, part);
  k_comb<<<NTG + NTS, 256, 0, stream>>>(part, bg, bs, out, pm, ps);
  dim3 gfin(FTG + FTS, NB);
  k_fin<<<gfin, 256, 0, stream>>>(pm, ps, out);
}